// Round 2
// baseline (1020.110 us; speedup 1.0000x reference)
//
#include <hip/hip_runtime.h>

// Problem constants (from reference setup_inputs)
constexpr int T = 16;       // tables
constexpr int E = 200000;   // rows per table
constexpr int D = 64;       // embedding dim
constexpr int B = 4096;     // batch
constexpr int L = 20;       // fixed bag length (still read offsets for safety)

// DIAGNOSTIC ROUND: same best-known kernel body, launched twice.
//   TAG=0: full grid (16384 blocks) -- the real, fast computation.
//   TAG=1: 256 blocks, grid-stride, rewrites identical values (idempotent) --
//          deliberately slow enough to surface in rocprof top-5 WITH counters
//          (FETCH_SIZE -> over-fetch check; hbm_gbps -> random-gather service
//          rate; dur -> exact t_B). dur_us_new - 927 - t_B = t_A exactly.
template <int TAG>
__global__ __launch_bounds__(256) void tbe_pooled_fwd(
    const int*   __restrict__ indices,   // [T*B*L]
    const int*   __restrict__ offsets,   // [T*B+1]
    const float* __restrict__ weights,   // [T, E, D]
    float*       __restrict__ out,       // [B, T*D]
    int num_groups)                      // T*B/4 groups of 4 bags
{
    const int lane = threadIdx.x & 63;
    const int wave = threadIdx.x >> 6;

    for (int g = blockIdx.x; g < num_groups; g += gridDim.x) {
        // Wave-uniform bag id -> scalar path for offsets/indices.
        const int bag = __builtin_amdgcn_readfirstlane(g * 4 + wave);
        const int t   = bag >> 12;           // bag / B   (B = 4096)
        const int b   = bag & (B - 1);       // bag % B

        const int start = offsets[bag];      // uniform -> s_load
        const int end   = offsets[bag + 1];
        const int n     = end - start;

        const float* tbl = weights + (size_t)t * (E * D);

        float acc = 0.f;

        if (n == L) {
            int idx[L];
#pragma unroll
            for (int l = 0; l < L; ++l)
                idx[l] = indices[start + l];             // uniform -> s_load
#pragma unroll
            for (int l = 0; l < L; ++l)
                acc += tbl[(uint32_t)idx[l] * D + lane]; // one 256B row / instr
        } else {
            for (int l = 0; l < n; ++l) {
                const int i = indices[start + l];
                acc += tbl[(uint32_t)i * D + lane];
            }
        }

        out[(size_t)b * (T * D) + t * D + lane] = acc;   // 256B/wave store
    }
}

extern "C" void kernel_launch(void* const* d_in, const int* in_sizes, int n_in,
                              void* d_out, int out_size, void* d_ws, size_t ws_size,
                              hipStream_t stream) {
    const int*   indices = (const int*)  d_in[0];
    const int*   offsets = (const int*)  d_in[1];
    const float* weights = (const float*)d_in[2];
    float*       out     = (float*)      d_out;

    const int num_groups = T * B / 4;        // 16384 groups (4 bags/block)

    // A: the real computation, identical to round-1 best.
    tbe_pooled_fwd<0><<<num_groups, 256, 0, stream>>>(
        indices, offsets, weights, out, num_groups);

    // B: idempotent diagnostic re-run at 1/64 parallelism (1 block/CU,
    // 4 waves/CU). Writes the same values to out -> correctness preserved.
    tbe_pooled_fwd<1><<<256, 256, 0, stream>>>(
        indices, offsets, weights, out, num_groups);
}